// Round 1
// baseline (274.064 us; speedup 1.0000x reference)
//
#include <hip/hip_runtime.h>
#include <hip/hip_bf16.h>
#include <stdint.h>

// Problem constants
#define N_SEQ 2048
#define BATCH 2
#define CDIM  1024
#define NH    16
#define HDIM  64
#define QK_SCALE 0.125f   // 64^-0.5

typedef __attribute__((ext_vector_type(8))) short bf16x8;  // 8 bf16 = 4 VGPRs
typedef __attribute__((ext_vector_type(4))) float f32x4;
typedef unsigned short u16;

__device__ __forceinline__ u16 f2bf(float f) {
  union { float f; unsigned u; } v; v.f = f;
  unsigned r = v.u + 0x7fffu + ((v.u >> 16) & 1u);   // RNE
  return (u16)(r >> 16);
}

// async global->LDS, 16B per lane. lds ptr must be wave-uniform base.
__device__ __forceinline__ void async_copy16(void* l, const void* g) {
  __builtin_amdgcn_global_load_lds(
      (const __attribute__((address_space(1))) unsigned int*)g,
      (__attribute__((address_space(3))) unsigned int*)l, 16, 0, 0);
}

// ---------------------------------------------------------------- casts
__global__ __launch_bounds__(256) void cast_f2b_kernel(
    const float* __restrict__ in, u16* __restrict__ out, int n) {
  int i = (blockIdx.x * 256 + threadIdx.x) * 4;
  if (i >= n) return;
  float4 v = *(const float4*)(in + i);
  ushort4 o;
  o.x = f2bf(v.x); o.y = f2bf(v.y); o.z = f2bf(v.z); o.w = f2bf(v.w);
  *(ushort4*)(out + i) = o;
}

// x (N,B,C) fp32 -> xb (B,N,C) bf16
__global__ __launch_bounds__(256) void cast_x_kernel(
    const float* __restrict__ x, u16* __restrict__ xb) {
  int i = blockIdx.x * 256 + threadIdx.x;       // over (n*B+b) * C/4
  int c  = (i & 255) << 2;                      // C/4 = 256 float4 groups
  int nb = i >> 8;                              // n*BATCH + b
  int n = nb >> 1, b = nb & 1;
  float4 v = *(const float4*)(x + (size_t)nb * CDIM + c);
  ushort4 o;
  o.x = f2bf(v.x); o.y = f2bf(v.y); o.z = f2bf(v.z); o.w = f2bf(v.w);
  *(ushort4*)(xb + ((size_t)(b * N_SEQ + n) * CDIM) + c) = o;
}

// ---------------------------------------------------- shared GEMM core
// C[M,N] = A[M,K] @ B[N,K]^T, bf16 in, f32 acc. 128x128 tile, BK=64,
// 4 waves in 2x2, each wave 64x64 = 4x4 frags of 16x16x32 MFMA.
// LDS XOR-swizzle (byte ^= (row&7)<<4) applied via pre-swizzled global
// source (global_load_lds writes linearly) + swizzled ds_read.
__device__ __forceinline__ void gemm128_core(
    const u16* __restrict__ A, const u16* __restrict__ B,
    int arow0, int brow0, int K,
    u16* lA, u16* lB, f32x4 acc[4][4]) {
  const int tid = threadIdx.x;
  const int w = tid >> 6, lane = tid & 63;
  const int wm = w >> 1, wn = w & 1;
  for (int k0 = 0; k0 < K; k0 += 64) {
    __syncthreads();   // protect prev iteration's reads (WAR)
    #pragma unroll
    for (int call = 0; call < 4; ++call) {
      int base = (call * 4 + w) * 64;          // wave-uniform chunk base
      int c = base + lane;                     // 16B chunk id, 8 per row
      int r = c >> 3;
      int scb = (c & 7) ^ (r & 7);             // pre-swizzled source chunk
      async_copy16(lA + base * 8, A + (size_t)(arow0 + r) * K + k0 + scb * 8);
      async_copy16(lB + base * 8, B + (size_t)(brow0 + r) * K + k0 + scb * 8);
    }
    __syncthreads();   // drains vmcnt(0) before barrier (compiler-emitted)
    #pragma unroll
    for (int ks = 0; ks < 2; ++ks) {
      bf16x8 af[4], bf[4];
      #pragma unroll
      for (int i = 0; i < 4; ++i) {
        int cb = ks * 4 + (lane >> 4);
        int ra = wm * 64 + i * 16 + (lane & 15);
        af[i] = *(const bf16x8*)(lA + ra * 64 + ((cb ^ (ra & 7)) << 3));
        int rb = wn * 64 + i * 16 + (lane & 15);
        bf[i] = *(const bf16x8*)(lB + rb * 64 + ((cb ^ (rb & 7)) << 3));
      }
      #pragma unroll
      for (int i = 0; i < 4; ++i)
        #pragma unroll
        for (int j = 0; j < 4; ++j)
          acc[i][j] = __builtin_amdgcn_mfma_f32_16x16x32_bf16(
              af[i], bf[j], acc[i][j], 0, 0, 0);
    }
  }
}

// ------------------------------------------------------------- GEMM 1
// xb (4096,1024) @ w_qkv(3072,1024)^T. Scatter into q,k (B,H,N,HD) and
// vT (B,H,HD,N), q scaled.
__global__ __launch_bounds__(256) void gemm_qkv_kernel(
    const u16* __restrict__ A, const u16* __restrict__ B,
    u16* __restrict__ qo, u16* __restrict__ ko, u16* __restrict__ vTo) {
  __shared__ __align__(16) u16 lA[128 * 64];
  __shared__ __align__(16) u16 lB[128 * 64];
  f32x4 acc[4][4] = {};
  const int arow0 = blockIdx.y * 128;
  const int brow0 = blockIdx.x * 128;
  gemm128_core(A, B, arow0, brow0, CDIM, lA, lB, acc);

  const int lane = threadIdx.x & 63;
  const int w = threadIdx.x >> 6;
  const int wm = w >> 1, wn = w & 1;
  #pragma unroll
  for (int fn = 0; fn < 4; ++fn) {
    int col0 = brow0 + wn * 64 + fn * 16;       // uniform per frag
    int sel = col0 >> 10;                       // 0=q 1=k 2=v
    int h   = (col0 >> 6) & 15;
    int d   = (col0 & 63) + (lane & 15);
    #pragma unroll
    for (int fm = 0; fm < 4; ++fm) {
      #pragma unroll
      for (int j = 0; j < 4; ++j) {
        int row = arow0 + wm * 64 + fm * 16 + ((lane >> 4) << 2) + j;
        int b = row >> 11, n = row & (N_SEQ - 1);
        float v = acc[fm][fn][j];
        size_t head = (size_t)(b * NH + h);
        if (sel == 0)
          qo[(head * N_SEQ + n) * HDIM + d] = f2bf(v * QK_SCALE);
        else if (sel == 1)
          ko[(head * N_SEQ + n) * HDIM + d] = f2bf(v);
        else
          vTo[(head * HDIM + d) * N_SEQ + n] = f2bf(v);
      }
    }
  }
}

// ------------------------------------------------------------- GEMM 2
// attn_out (4096,1024) @ w_proj(1024,1024)^T + b_proj -> out (N,B,C) fp32
__global__ __launch_bounds__(256) void gemm_proj_kernel(
    const u16* __restrict__ A, const u16* __restrict__ B,
    const float* __restrict__ bias, float* __restrict__ out) {
  __shared__ __align__(16) u16 lA[128 * 64];
  __shared__ __align__(16) u16 lB[128 * 64];
  f32x4 acc[4][4] = {};
  const int arow0 = blockIdx.y * 128;
  const int brow0 = blockIdx.x * 128;
  gemm128_core(A, B, arow0, brow0, CDIM, lA, lB, acc);

  const int lane = threadIdx.x & 63;
  const int w = threadIdx.x >> 6;
  const int wm = w >> 1, wn = w & 1;
  #pragma unroll
  for (int fn = 0; fn < 4; ++fn) {
    int col = brow0 + wn * 64 + fn * 16 + (lane & 15);
    float bv = bias[col];
    #pragma unroll
    for (int fm = 0; fm < 4; ++fm) {
      #pragma unroll
      for (int j = 0; j < 4; ++j) {
        int row = arow0 + wm * 64 + fm * 16 + ((lane >> 4) << 2) + j;
        int b = row >> 11, n = row & (N_SEQ - 1);
        out[((size_t)n * BATCH + b) * CDIM + col] = acc[fm][fn][j] + bv;
      }
    }
  }
}

// ---------------------------------------------------- flash attention
// 1 WG = 4 waves per (b,h,q-tile of 64). Each wave owns 16 q rows.
// KV blocks of 64. Q pre-scaled. K (N,HD) and V^T (HD,N) staged via
// global_load_lds with XOR swizzle; P round-trips through swizzled LDS.
__global__ __launch_bounds__(256) void attn_kernel(
    const u16* __restrict__ q, const u16* __restrict__ k,
    const u16* __restrict__ vT, u16* __restrict__ attn_out) {
  const int tid = threadIdx.x, w = tid >> 6, lane = tid & 63;
  const int bh = blockIdx.x >> 5;     // 0..31  (b*NH + h)
  const int qt = blockIdx.x & 31;
  const int b = bh >> 4, h = bh & 15;
  const u16* Q  = q  + (size_t)bh * N_SEQ * HDIM;
  const u16* K  = k  + (size_t)bh * N_SEQ * HDIM;
  const u16* VT = vT + (size_t)bh * HDIM * N_SEQ;
  const int q0 = qt * 64;

  __shared__ __align__(16) u16 Ks[64 * 64];
  __shared__ __align__(16) u16 VTs[64 * 64];
  __shared__ __align__(16) u16 Ps[4][16 * 64];

  // Q A-fragments in registers (rows q0+w*16 .. +16)
  bf16x8 qa[2];
  {
    int qrow = q0 + w * 16 + (lane & 15);
    #pragma unroll
    for (int ks = 0; ks < 2; ++ks)
      qa[ks] = *(const bf16x8*)(Q + (size_t)qrow * HDIM + ks * 32 + (lane >> 4) * 8);
  }

  f32x4 o[4] = {};
  float mrow[4], lrow[4];
  #pragma unroll
  for (int j = 0; j < 4; ++j) { mrow[j] = -1e30f; lrow[j] = 0.f; }

  for (int kv0 = 0; kv0 < N_SEQ; kv0 += 64) {
    __syncthreads();
    // stage K block (64x64) and VT block (64 hd-rows x 64 kv-cols)
    #pragma unroll
    for (int call = 0; call < 2; ++call) {
      int base = (call * 4 + w) * 64;
      int c = base + lane;
      int r = c >> 3;
      int scb = (c & 7) ^ (r & 7);
      async_copy16(Ks + base * 8, K + (size_t)(kv0 + r) * HDIM + scb * 8);
      async_copy16(VTs + base * 8, VT + (size_t)r * N_SEQ + kv0 + scb * 8);
    }
    __syncthreads();

    // S = Q K^T  (wave's 16 rows x 64 kv cols)
    f32x4 s[4] = {};
    #pragma unroll
    for (int ks = 0; ks < 2; ++ks) {
      #pragma unroll
      for (int fn = 0; fn < 4; ++fn) {
        int r = fn * 16 + (lane & 15);
        int cb = ks * 4 + (lane >> 4);
        bf16x8 kb = *(const bf16x8*)(Ks + r * 64 + ((cb ^ (r & 7)) << 3));
        s[fn] = __builtin_amdgcn_mfma_f32_16x16x32_bf16(qa[ks], kb, s[fn], 0, 0, 0);
      }
    }

    // online softmax, rows live in 16-lane groups (bits 0-3 of lane)
    #pragma unroll
    for (int j = 0; j < 4; ++j) {
      float mx = s[0][j];
      mx = fmaxf(mx, s[1][j]); mx = fmaxf(mx, s[2][j]); mx = fmaxf(mx, s[3][j]);
      mx = fmaxf(mx, __shfl_xor(mx, 1));
      mx = fmaxf(mx, __shfl_xor(mx, 2));
      mx = fmaxf(mx, __shfl_xor(mx, 4));
      mx = fmaxf(mx, __shfl_xor(mx, 8));
      float mnew = fmaxf(mrow[j], mx);
      float corr = __expf(mrow[j] - mnew);
      float rs = 0.f;
      #pragma unroll
      for (int fn = 0; fn < 4; ++fn) {
        float p = __expf(s[fn][j] - mnew);
        s[fn][j] = p; rs += p;
      }
      rs += __shfl_xor(rs, 1);
      rs += __shfl_xor(rs, 2);
      rs += __shfl_xor(rs, 4);
      rs += __shfl_xor(rs, 8);
      lrow[j] = lrow[j] * corr + rs;
      mrow[j] = mnew;
      #pragma unroll
      for (int fn = 0; fn < 4; ++fn) o[fn][j] *= corr;
    }

    // P -> LDS (swizzled), then PV
    u16* Pw = Ps[w];
    #pragma unroll
    for (int fn = 0; fn < 4; ++fn) {
      int col = fn * 16 + (lane & 15);
      int cb = col >> 3;
      #pragma unroll
      for (int j = 0; j < 4; ++j) {
        int row = ((lane >> 4) << 2) + j;
        Pw[row * 64 + ((cb ^ (row & 7)) << 3) + (col & 7)] = f2bf(s[fn][j]);
      }
    }
    asm volatile("s_waitcnt lgkmcnt(0)" ::: "memory");  // wave-local P visibility

    #pragma unroll
    for (int ks = 0; ks < 2; ++ks) {
      int cb = ks * 4 + (lane >> 4);
      int rp = lane & 15;
      bf16x8 pa = *(const bf16x8*)(Pw + rp * 64 + ((cb ^ (rp & 7)) << 3));
      #pragma unroll
      for (int fn = 0; fn < 4; ++fn) {
        int r = fn * 16 + (lane & 15);
        bf16x8 vb = *(const bf16x8*)(VTs + r * 64 + ((cb ^ (r & 7)) << 3));
        o[fn] = __builtin_amdgcn_mfma_f32_16x16x32_bf16(pa, vb, o[fn], 0, 0, 0);
      }
    }
  }

  // epilogue: O/l -> attn_out (B*N, C) bf16
  #pragma unroll
  for (int fn = 0; fn < 4; ++fn) {
    int col = h * HDIM + fn * 16 + (lane & 15);
    #pragma unroll
    for (int j = 0; j < 4; ++j) {
      int rowg = q0 + w * 16 + ((lane >> 4) << 2) + j;
      attn_out[((size_t)(b * N_SEQ + rowg)) * CDIM + col] = f2bf(o[fn][j] / lrow[j]);
    }
  }
}

// -------------------------------------------------------------- launch
extern "C" void kernel_launch(void* const* d_in, const int* in_sizes, int n_in,
                              void* d_out, int out_size, void* d_ws, size_t ws_size,
                              hipStream_t stream) {
  (void)in_sizes; (void)n_in; (void)out_size; (void)ws_size;
  const float* x      = (const float*)d_in[0];
  const float* w_qkv  = (const float*)d_in[1];
  const float* w_proj = (const float*)d_in[2];
  const float* b_proj = (const float*)d_in[3];
  float* out = (float*)d_out;

  char* ws = (char*)d_ws;
  // workspace layout (bytes)
  u16* xb     = (u16*)(ws);                       //  8.39 MB (B*N, C)
  u16* wqkvb  = (u16*)(ws + 8388608);             //  6.29 MB (3C, C)
  u16* wprojb = (u16*)(ws + 14680064);            //  2.10 MB (C, C)
  u16* qd     = (u16*)(ws + 16777216);            //  8.39 MB (B,H,N,HD)
  u16* kd     = (u16*)(ws + 25165824);            //  8.39 MB (B,H,N,HD)
  u16* vTd    = (u16*)(ws + 33554432);            //  8.39 MB (B,H,HD,N)
  u16* attn_o = (u16*)(ws + 41943040);            //  8.39 MB (B*N, C)

  cast_f2b_kernel<<<3072, 256, 0, stream>>>(w_qkv, wqkvb, 3 * CDIM * CDIM);
  cast_f2b_kernel<<<1024, 256, 0, stream>>>(w_proj, wprojb, CDIM * CDIM);
  cast_x_kernel<<<4096, 256, 0, stream>>>(x, xb);

  gemm_qkv_kernel<<<dim3(24, 32), 256, 0, stream>>>(xb, wqkvb, qd, kd, vTd);
  attn_kernel<<<1024, 256, 0, stream>>>(qd, kd, vTd, attn_o);
  gemm_proj_kernel<<<dim3(8, 32), 256, 0, stream>>>(attn_o, wprojb, b_proj, out);
}

// Round 6
// 222.371 us; speedup vs baseline: 1.2325x; 1.2325x over previous
//
#include <hip/hip_runtime.h>
#include <hip/hip_bf16.h>
#include <stdint.h>

// Problem constants
#define N_SEQ 2048
#define BATCH 2
#define CDIM  1024
#define NH    16
#define HDIM  64
// softmax pre-scale: HD^-0.5 * log2(e)  (lets us use raw v_exp_f32 = 2^x)
#define SM_PRESCALE 0.18033688f

typedef __attribute__((ext_vector_type(8))) short bf16x8;  // 8 bf16 = 4 VGPRs
typedef __attribute__((ext_vector_type(4))) float f32x4;
typedef unsigned short u16;

__device__ __forceinline__ u16 f2bf(float f) {
  union { float f; unsigned u; } v; v.f = f;
  unsigned r = v.u + 0x7fffu + ((v.u >> 16) & 1u);   // RNE
  return (u16)(r >> 16);
}

__device__ __forceinline__ float exp2_fast(float x) {
  float r;
  asm("v_exp_f32 %0, %1" : "=v"(r) : "v"(x));
  return r;
}

// async global->LDS, 16B per lane. lds ptr must be wave-uniform base.
__device__ __forceinline__ void async_copy16(void* l, const void* g) {
  __builtin_amdgcn_global_load_lds(
      (const __attribute__((address_space(1))) unsigned int*)g,
      (__attribute__((address_space(3))) unsigned int*)l, 16, 0, 0);
}

// ---------------------------------------------------------------- casts
__global__ __launch_bounds__(256) void cast_f2b_kernel(
    const float* __restrict__ in, u16* __restrict__ out, int n) {
  int i = (blockIdx.x * 256 + threadIdx.x) * 4;
  if (i >= n) return;
  float4 v = *(const float4*)(in + i);
  ushort4 o;
  o.x = f2bf(v.x); o.y = f2bf(v.y); o.z = f2bf(v.z); o.w = f2bf(v.w);
  *(ushort4*)(out + i) = o;
}

// x (N,B,C) fp32 -> xb (B,N,C) bf16
__global__ __launch_bounds__(256) void cast_x_kernel(
    const float* __restrict__ x, u16* __restrict__ xb) {
  int i = blockIdx.x * 256 + threadIdx.x;       // over (n*B+b) * C/4
  int c  = (i & 255) << 2;                      // C/4 = 256 float4 groups
  int nb = i >> 8;                              // n*BATCH + b
  int n = nb >> 1, b = nb & 1;
  float4 v = *(const float4*)(x + (size_t)nb * CDIM + c);
  ushort4 o;
  o.x = f2bf(v.x); o.y = f2bf(v.y); o.z = f2bf(v.z); o.w = f2bf(v.w);
  *(ushort4*)(xb + ((size_t)(b * N_SEQ + n) * CDIM) + c) = o;
}

// ---------------------------------------------------- shared GEMM core
// C[M,N] = A[M,K] @ B[N,K]^T, bf16 in, f32 acc. 128x128 tile, BK=64,
// 4 waves in 2x2, each wave 64x64 = 4x4 frags of 16x16x32 MFMA.
// LDS XOR-swizzle (byte ^= (row&7)<<4) applied via pre-swizzled global
// source (global_load_lds writes linearly) + swizzled ds_read.
__device__ __forceinline__ void gemm128_core(
    const u16* __restrict__ A, const u16* __restrict__ B,
    int arow0, int brow0, int K,
    u16* lA, u16* lB, f32x4 acc[4][4]) {
  const int tid = threadIdx.x;
  const int w = tid >> 6, lane = tid & 63;
  const int wm = w >> 1, wn = w & 1;
  for (int k0 = 0; k0 < K; k0 += 64) {
    __syncthreads();   // protect prev iteration's reads (WAR)
    #pragma unroll
    for (int call = 0; call < 4; ++call) {
      int base = (call * 4 + w) * 64;          // wave-uniform chunk base
      int c = base + lane;                     // 16B chunk id, 8 per row
      int r = c >> 3;
      int scb = (c & 7) ^ (r & 7);             // pre-swizzled source chunk
      async_copy16(lA + base * 8, A + (size_t)(arow0 + r) * K + k0 + scb * 8);
      async_copy16(lB + base * 8, B + (size_t)(brow0 + r) * K + k0 + scb * 8);
    }
    __syncthreads();   // drains vmcnt(0) before barrier (compiler-emitted)
    #pragma unroll
    for (int ks = 0; ks < 2; ++ks) {
      bf16x8 af[4], bf[4];
      #pragma unroll
      for (int i = 0; i < 4; ++i) {
        int cb = ks * 4 + (lane >> 4);
        int ra = wm * 64 + i * 16 + (lane & 15);
        af[i] = *(const bf16x8*)(lA + ra * 64 + ((cb ^ (ra & 7)) << 3));
        int rb = wn * 64 + i * 16 + (lane & 15);
        bf[i] = *(const bf16x8*)(lB + rb * 64 + ((cb ^ (rb & 7)) << 3));
      }
      #pragma unroll
      for (int i = 0; i < 4; ++i)
        #pragma unroll
        for (int j = 0; j < 4; ++j)
          acc[i][j] = __builtin_amdgcn_mfma_f32_16x16x32_bf16(
              af[i], bf[j], acc[i][j], 0, 0, 0);
    }
  }
}

// ------------------------------------------------------------- GEMM 1
// xb (4096,1024) @ w_qkv(3072,1024)^T. Scatter into q,k (B,H,N,HD) and
// vT (B,H,HD,N). q pre-scaled by SCALE*log2e for the exp2 softmax.
__global__ __launch_bounds__(256) void gemm_qkv_kernel(
    const u16* __restrict__ A, const u16* __restrict__ B,
    u16* __restrict__ qo, u16* __restrict__ ko, u16* __restrict__ vTo) {
  __shared__ __align__(16) u16 lA[128 * 64];
  __shared__ __align__(16) u16 lB[128 * 64];
  f32x4 acc[4][4] = {};
  const int arow0 = blockIdx.y * 128;
  const int brow0 = blockIdx.x * 128;
  gemm128_core(A, B, arow0, brow0, CDIM, lA, lB, acc);

  const int lane = threadIdx.x & 63;
  const int w = threadIdx.x >> 6;
  const int wm = w >> 1, wn = w & 1;
  #pragma unroll
  for (int fn = 0; fn < 4; ++fn) {
    int col0 = brow0 + wn * 64 + fn * 16;       // uniform per frag
    int sel = col0 >> 10;                       // 0=q 1=k 2=v
    int h   = (col0 >> 6) & 15;
    int d   = (col0 & 63) + (lane & 15);
    #pragma unroll
    for (int fm = 0; fm < 4; ++fm) {
      #pragma unroll
      for (int j = 0; j < 4; ++j) {
        int row = arow0 + wm * 64 + fm * 16 + ((lane >> 4) << 2) + j;
        int b = row >> 11, n = row & (N_SEQ - 1);
        float v = acc[fm][fn][j];
        size_t head = (size_t)(b * NH + h);
        if (sel == 0)
          qo[(head * N_SEQ + n) * HDIM + d] = f2bf(v * SM_PRESCALE);
        else if (sel == 1)
          ko[(head * N_SEQ + n) * HDIM + d] = f2bf(v);
        else
          vTo[(head * HDIM + d) * N_SEQ + n] = f2bf(v);
      }
    }
  }
}

// ------------------------------------------------------------- GEMM 2
// attn_out (4096,1024) @ w_proj(1024,1024)^T + b_proj -> out (N,B,C) fp32
__global__ __launch_bounds__(256) void gemm_proj_kernel(
    const u16* __restrict__ A, const u16* __restrict__ B,
    const float* __restrict__ bias, float* __restrict__ out) {
  __shared__ __align__(16) u16 lA[128 * 64];
  __shared__ __align__(16) u16 lB[128 * 64];
  f32x4 acc[4][4] = {};
  const int arow0 = blockIdx.y * 128;
  const int brow0 = blockIdx.x * 128;
  gemm128_core(A, B, arow0, brow0, CDIM, lA, lB, acc);

  const int lane = threadIdx.x & 63;
  const int w = threadIdx.x >> 6;
  const int wm = w >> 1, wn = w & 1;
  #pragma unroll
  for (int fn = 0; fn < 4; ++fn) {
    int col = brow0 + wn * 64 + fn * 16 + (lane & 15);
    float bv = bias[col];
    #pragma unroll
    for (int fm = 0; fm < 4; ++fm) {
      #pragma unroll
      for (int j = 0; j < 4; ++j) {
        int row = arow0 + wm * 64 + fm * 16 + ((lane >> 4) << 2) + j;
        int b = row >> 11, n = row & (N_SEQ - 1);
        out[((size_t)n * BATCH + b) * CDIM + col] = acc[fm][fn][j] + bv;
      }
    }
  }
}

// ---------------------------------------------------- flash attention
// Swapped QK^T structure: S^T = mfma(K, Q) puts q = lane&15, so each lane
// owns one q-row's kv values in registers. K rows are staged in LDS in a
// bit-shuffled order pi(32a+16b+4g+j) = 32a+8g+4b+j so the post-softmax P
// registers are already in exact B-fragment order for the PV mfma -> P
// never touches LDS. O is accumulated transposed (D[d][q]); m/l/corr are
// per-lane scalars. Softmax uses raw v_exp_f32 (Q pre-scaled by log2e).
__global__ __launch_bounds__(256) void attn_kernel(
    const u16* __restrict__ q, const u16* __restrict__ k,
    const u16* __restrict__ vT, u16* __restrict__ attn_out) {
  const int tid = threadIdx.x, w = tid >> 6, lane = tid & 63;
  // bijective XCD-chunked swizzle: 1024 blocks, 128 consecutive per XCD
  const int swz = (blockIdx.x & 7) * 128 + (blockIdx.x >> 3);
  const int bh = swz >> 5;            // 0..31  (b*NH + h)
  const int qt = swz & 31;
  const int b = bh >> 4, h = bh & 15;
  const u16* Q  = q  + (size_t)bh * N_SEQ * HDIM;
  const u16* K  = k  + (size_t)bh * N_SEQ * HDIM;
  const u16* VT = vT + (size_t)bh * HDIM * N_SEQ;
  const int q0 = qt * 64;
  const int lg = lane >> 4;           // 16-lane group 0..3

  __shared__ __align__(16) u16 Ks[64 * 64];
  __shared__ __align__(16) u16 VTs[64 * 64];

  // Q B-fragments in registers: lane holds Q[q0+w*16+(lane&15)][d-chunk]
  bf16x8 qa[2];
  {
    int qrow = q0 + w * 16 + (lane & 15);
    #pragma unroll
    for (int ks = 0; ks < 2; ++ks)
      qa[ks] = *(const bf16x8*)(Q + (size_t)qrow * HDIM + ks * 32 + lg * 8);
  }

  f32x4 o[4] = {};                    // O^T frag: d = fd*16 + 4*lg + j
  float m = -1e30f, l = 0.f;

  for (int kv0 = 0; kv0 < N_SEQ; kv0 += 64) {
    __syncthreads();                  // WAR on prev iteration's LDS reads
    #pragma unroll
    for (int call = 0; call < 2; ++call) {
      int base = (call * 4 + w) * 64;
      int c = base + lane;
      int r = c >> 3;
      int scb = (c & 7) ^ (r & 7);    // pre-swizzled source chunk
      // pi(r): K row permutation making P regs land in B-frag order
      int pr = (r & 32) | ((r & 12) << 1) | ((r & 16) >> 2) | (r & 3);
      async_copy16(Ks + base * 8, K + (size_t)(kv0 + pr) * HDIM + scb * 8);
      async_copy16(VTs + base * 8, VT + (size_t)r * N_SEQ + kv0 + scb * 8);
    }
    __syncthreads();                  // drains vmcnt(0) (compiler-emitted)

    // S^T = K Q^T : lane owns q-row (lane&15), 16 kv values in regs
    f32x4 s[4] = {};
    __builtin_amdgcn_s_setprio(1);
    #pragma unroll
    for (int ks = 0; ks < 2; ++ks) {
      #pragma unroll
      for (int fn = 0; fn < 4; ++fn) {
        int r = fn * 16 + (lane & 15);
        int cb = ks * 4 + lg;
        bf16x8 kb = *(const bf16x8*)(Ks + r * 64 + ((cb ^ (r & 7)) << 3));
        s[fn] = __builtin_amdgcn_mfma_f32_16x16x32_bf16(kb, qa[ks], s[fn], 0, 0, 0);
      }
    }
    __builtin_amdgcn_s_setprio(0);

    // online softmax (log2 domain), per-lane scalar state
    float mx = s[0][0];
    #pragma unroll
    for (int fn = 0; fn < 4; ++fn)
      #pragma unroll
      for (int j = 0; j < 4; ++j) mx = fmaxf(mx, s[fn][j]);
    mx = fmaxf(mx, __shfl_xor(mx, 16));
    mx = fmaxf(mx, __shfl_xor(mx, 32));
    // defer-max (T13): only rescale when max grew by > 8 nats (11.54 log2)
    if (__any(mx > m + 11.5416f)) {
      float mnew = fmaxf(m, mx);
      float corr = exp2_fast(m - mnew);
      m = mnew;
      l *= corr;
      #pragma unroll
      for (int fd = 0; fd < 4; ++fd)
        #pragma unroll
        for (int j = 0; j < 4; ++j) o[fd][j] *= corr;
    }
    float rs = 0.f;
    #pragma unroll
    for (int fn = 0; fn < 4; ++fn)
      #pragma unroll
      for (int j = 0; j < 4; ++j) {
        float p = exp2_fast(s[fn][j] - m);
        s[fn][j] = p; rs += p;
      }
    rs += __shfl_xor(rs, 16);
    rs += __shfl_xor(rs, 32);
    l += rs;

    // PV: O^T += V^T P^T. P regs are already in B-frag order (pi trick).
    #pragma unroll
    for (int ks = 0; ks < 2; ++ks) {
      bf16x8 pa;
      #pragma unroll
      for (int e = 0; e < 4; ++e) {
        pa[e]     = (short)f2bf(s[2 * ks][e]);
        pa[4 + e] = (short)f2bf(s[2 * ks + 1][e]);
      }
      __builtin_amdgcn_s_setprio(1);
      #pragma unroll
      for (int fd = 0; fd < 4; ++fd) {
        int rv = fd * 16 + (lane & 15);
        int cb = ks * 4 + lg;
        bf16x8 vb = *(const bf16x8*)(VTs + rv * 64 + ((cb ^ (rv & 7)) << 3));
        o[fd] = __builtin_amdgcn_mfma_f32_16x16x32_bf16(vb, pa, o[fd], 0, 0, 0);
      }
      __builtin_amdgcn_s_setprio(0);
    }
  }

  // epilogue: O^T/l -> attn_out (B*N, C) bf16. Lane owns one q-row;
  // its 4 d-values per fd are contiguous -> ushort4 stores.
  float inv = 1.0f / l;
  int qrow = q0 + w * 16 + (lane & 15);
  u16* dst = attn_out + ((size_t)(b * N_SEQ + qrow)) * CDIM + h * HDIM;
  #pragma unroll
  for (int fd = 0; fd < 4; ++fd) {
    ushort4 ov;
    ov.x = f2bf(o[fd][0] * inv);
    ov.y = f2bf(o[fd][1] * inv);
    ov.z = f2bf(o[fd][2] * inv);
    ov.w = f2bf(o[fd][3] * inv);
    *(ushort4*)(dst + fd * 16 + (lg << 2)) = ov;
  }
}

// -------------------------------------------------------------- launch
extern "C" void kernel_launch(void* const* d_in, const int* in_sizes, int n_in,
                              void* d_out, int out_size, void* d_ws, size_t ws_size,
                              hipStream_t stream) {
  (void)in_sizes; (void)n_in; (void)out_size; (void)ws_size;
  const float* x      = (const float*)d_in[0];
  const float* w_qkv  = (const float*)d_in[1];
  const float* w_proj = (const float*)d_in[2];
  const float* b_proj = (const float*)d_in[3];
  float* out = (float*)d_out;

  char* ws = (char*)d_ws;
  // workspace layout (bytes)
  u16* xb     = (u16*)(ws);                       //  8.39 MB (B*N, C)
  u16* wqkvb  = (u16*)(ws + 8388608);             //  6.29 MB (3C, C)
  u16* wprojb = (u16*)(ws + 14680064);            //  2.10 MB (C, C)
  u16* qd     = (u16*)(ws + 16777216);            //  8.39 MB (B,H,N,HD)
  u16* kd     = (u16*)(ws + 25165824);            //  8.39 MB (B,H,N,HD)
  u16* vTd    = (u16*)(ws + 33554432);            //  8.39 MB (B,H,HD,N)
  u16* attn_o = (u16*)(ws + 41943040);            //  8.39 MB (B*N, C)

  cast_f2b_kernel<<<3072, 256, 0, stream>>>(w_qkv, wqkvb, 3 * CDIM * CDIM);
  cast_f2b_kernel<<<1024, 256, 0, stream>>>(w_proj, wprojb, CDIM * CDIM);
  cast_x_kernel<<<4096, 256, 0, stream>>>(x, xb);

  gemm_qkv_kernel<<<dim3(24, 32), 256, 0, stream>>>(xb, wqkvb, qd, kd, vTd);
  attn_kernel<<<1024, 256, 0, stream>>>(qd, kd, vTd, attn_o);
  gemm_proj_kernel<<<dim3(8, 32), 256, 0, stream>>>(attn_o, wprojb, b_proj, out);
}

// Round 9
// 216.702 us; speedup vs baseline: 1.2647x; 1.0262x over previous
//
#include <hip/hip_runtime.h>
#include <hip/hip_bf16.h>
#include <stdint.h>

// Problem constants
#define N_SEQ 2048
#define BATCH 2
#define CDIM  1024
#define NH    16
#define HDIM  64
// softmax pre-scale: HD^-0.5 * log2(e)  (lets us use raw v_exp_f32 = 2^x)
#define SM_PRESCALE 0.18033688f

typedef __attribute__((ext_vector_type(8))) short bf16x8;  // 8 bf16 = 4 VGPRs
typedef __attribute__((ext_vector_type(4))) float f32x4;
typedef unsigned short u16;

__device__ __forceinline__ u16 f2bf(float f) {
  union { float f; unsigned u; } v; v.f = f;
  unsigned r = v.u + 0x7fffu + ((v.u >> 16) & 1u);   // RNE
  return (u16)(r >> 16);
}

__device__ __forceinline__ float exp2_fast(float x) {
  float r;
  asm("v_exp_f32 %0, %1" : "=v"(r) : "v"(x));
  return r;
}

// pack 2 f32 -> 2 bf16 in one u32 (D[15:0]=bf16(lo), D[31:16]=bf16(hi))
__device__ __forceinline__ uint32_t cvtpk_bf16(float lo, float hi) {
  uint32_t r;
  asm("v_cvt_pk_bf16_f32 %0, %1, %2" : "=v"(r) : "v"(lo), "v"(hi));
  return r;
}

// async global->LDS, 16B per lane. lds ptr must be wave-uniform base.
__device__ __forceinline__ void async_copy16(void* l, const void* g) {
  __builtin_amdgcn_global_load_lds(
      (const __attribute__((address_space(1))) unsigned int*)g,
      (__attribute__((address_space(3))) unsigned int*)l, 16, 0, 0);
}

// ---------------------------------------------------------------- casts
__global__ __launch_bounds__(256) void cast_f2b_kernel(
    const float* __restrict__ in, u16* __restrict__ out, int n) {
  int i = (blockIdx.x * 256 + threadIdx.x) * 4;
  if (i >= n) return;
  float4 v = *(const float4*)(in + i);
  ushort4 o;
  o.x = f2bf(v.x); o.y = f2bf(v.y); o.z = f2bf(v.z); o.w = f2bf(v.w);
  *(ushort4*)(out + i) = o;
}

// x (N,B,C) fp32 -> xb (B,N,C) bf16
__global__ __launch_bounds__(256) void cast_x_kernel(
    const float* __restrict__ x, u16* __restrict__ xb) {
  int i = blockIdx.x * 256 + threadIdx.x;       // over (n*B+b) * C/4
  int c  = (i & 255) << 2;                      // C/4 = 256 float4 groups
  int nb = i >> 8;                              // n*BATCH + b
  int n = nb >> 1, b = nb & 1;
  float4 v = *(const float4*)(x + (size_t)nb * CDIM + c);
  ushort4 o;
  o.x = f2bf(v.x); o.y = f2bf(v.y); o.z = f2bf(v.z); o.w = f2bf(v.w);
  *(ushort4*)(xb + ((size_t)(b * N_SEQ + n) * CDIM) + c) = o;
}

// ---------------------------------------------------- shared GEMM core
// C[M,N] = A[M,K] @ B[N,K]^T, bf16 in, f32 acc. Block = (FM*32) x 128,
// BK=64, 4 waves in 2x2, each wave (FM*16) x 64 = FM x 4 frags of
// 16x16x32 MFMA. LDS XOR-swizzle via pre-swizzled global source
// (global_load_lds writes linearly) + swizzled ds_read.
template<int FM>
__device__ __forceinline__ void gemm_core_t(
    const u16* __restrict__ A, const u16* __restrict__ B,
    int arow0, int brow0, int K,
    u16* lA, u16* lB, f32x4 acc[FM][4]) {
  const int tid = threadIdx.x;
  const int w = tid >> 6, lane = tid & 63;
  const int wm = w >> 1, wn = w & 1;
  for (int k0 = 0; k0 < K; k0 += 64) {
    __syncthreads();   // protect prev iteration's reads (WAR)
    #pragma unroll
    for (int call = 0; call < FM; ++call) {    // A: FM*32 rows * 8 chunks
      int base = (call * 4 + w) * 64;          // wave-uniform chunk base
      int c = base + lane;                     // 16B chunk id, 8 per row
      int r = c >> 3;
      int scb = (c & 7) ^ (r & 7);             // pre-swizzled source chunk
      async_copy16(lA + base * 8, A + (size_t)(arow0 + r) * K + k0 + scb * 8);
    }
    #pragma unroll
    for (int call = 0; call < 4; ++call) {     // B: 128 rows * 8 chunks
      int base = (call * 4 + w) * 64;
      int c = base + lane;
      int r = c >> 3;
      int scb = (c & 7) ^ (r & 7);
      async_copy16(lB + base * 8, B + (size_t)(brow0 + r) * K + k0 + scb * 8);
    }
    __syncthreads();   // drains vmcnt(0) before barrier (compiler-emitted)
    #pragma unroll
    for (int ks = 0; ks < 2; ++ks) {
      bf16x8 af[FM], bf[4];
      #pragma unroll
      for (int i = 0; i < FM; ++i) {
        int cb = ks * 4 + (lane >> 4);
        int ra = wm * (FM * 16) + i * 16 + (lane & 15);
        af[i] = *(const bf16x8*)(lA + ra * 64 + ((cb ^ (ra & 7)) << 3));
      }
      #pragma unroll
      for (int i = 0; i < 4; ++i) {
        int cb = ks * 4 + (lane >> 4);
        int rb = wn * 64 + i * 16 + (lane & 15);
        bf[i] = *(const bf16x8*)(lB + rb * 64 + ((cb ^ (rb & 7)) << 3));
      }
      #pragma unroll
      for (int i = 0; i < FM; ++i)
        #pragma unroll
        for (int j = 0; j < 4; ++j)
          acc[i][j] = __builtin_amdgcn_mfma_f32_16x16x32_bf16(
              af[i], bf[j], acc[i][j], 0, 0, 0);
    }
  }
}

// ------------------------------------------------------------- GEMM 1
// xb (4096,1024) @ w_qkv(3072,1024)^T. Scatter into q,k (B,H,N,HD) and
// vT (B,H,HD,N). q pre-scaled by SCALE*log2e for the exp2 softmax.
__global__ __launch_bounds__(256) void gemm_qkv_kernel(
    const u16* __restrict__ A, const u16* __restrict__ B,
    u16* __restrict__ qo, u16* __restrict__ ko, u16* __restrict__ vTo) {
  __shared__ __align__(16) u16 lA[128 * 64];
  __shared__ __align__(16) u16 lB[128 * 64];
  f32x4 acc[4][4] = {};
  const int arow0 = blockIdx.y * 128;
  const int brow0 = blockIdx.x * 128;
  gemm_core_t<4>(A, B, arow0, brow0, CDIM, lA, lB, acc);

  const int lane = threadIdx.x & 63;
  const int w = threadIdx.x >> 6;
  const int wm = w >> 1, wn = w & 1;
  #pragma unroll
  for (int fn = 0; fn < 4; ++fn) {
    int col0 = brow0 + wn * 64 + fn * 16;       // uniform per frag
    int sel = col0 >> 10;                       // 0=q 1=k 2=v
    int h   = (col0 >> 6) & 15;
    int d   = (col0 & 63) + (lane & 15);
    #pragma unroll
    for (int fm = 0; fm < 4; ++fm) {
      #pragma unroll
      for (int j = 0; j < 4; ++j) {
        int row = arow0 + wm * 64 + fm * 16 + ((lane >> 4) << 2) + j;
        int b = row >> 11, n = row & (N_SEQ - 1);
        float v = acc[fm][fn][j];
        size_t head = (size_t)(b * NH + h);
        if (sel == 0)
          qo[(head * N_SEQ + n) * HDIM + d] = f2bf(v * SM_PRESCALE);
        else if (sel == 1)
          ko[(head * N_SEQ + n) * HDIM + d] = f2bf(v);
        else
          vTo[(head * HDIM + d) * N_SEQ + n] = f2bf(v);
      }
    }
  }
}

// ------------------------------------------------------------- GEMM 2
// attn_out (4096,1024) @ w_proj(1024,1024)^T + b_proj -> out (N,B,C) fp32
// BM=64 tiles -> 512 blocks = 2/CU (vs 1/CU at BM=128: barrier stalls
// were exposed with no co-resident block to overlap).
__global__ __launch_bounds__(256) void gemm_proj_kernel(
    const u16* __restrict__ A, const u16* __restrict__ B,
    const float* __restrict__ bias, float* __restrict__ out) {
  __shared__ __align__(16) u16 lA[64 * 64];
  __shared__ __align__(16) u16 lB[128 * 64];
  f32x4 acc[2][4] = {};
  const int arow0 = blockIdx.y * 64;
  const int brow0 = blockIdx.x * 128;
  gemm_core_t<2>(A, B, arow0, brow0, CDIM, lA, lB, acc);

  const int lane = threadIdx.x & 63;
  const int w = threadIdx.x >> 6;
  const int wm = w >> 1, wn = w & 1;
  #pragma unroll
  for (int fn = 0; fn < 4; ++fn) {
    int col = brow0 + wn * 64 + fn * 16 + (lane & 15);
    float bv = bias[col];
    #pragma unroll
    for (int fm = 0; fm < 2; ++fm) {
      #pragma unroll
      for (int j = 0; j < 4; ++j) {
        int row = arow0 + wm * 32 + fm * 16 + ((lane >> 4) << 2) + j;
        int b = row >> 11, n = row & (N_SEQ - 1);
        out[((size_t)n * BATCH + b) * CDIM + col] = acc[fm][fn][j] + bv;
      }
    }
  }
}

// ---------------------------------------------------- flash attention
// Swapped QK^T structure: S^T = mfma(K, Q) puts q = lane&15, so each lane
// owns one q-row's kv values in registers. K rows are staged in LDS in a
// bit-shuffled order pi(32a+16b+4g+j) = 32a+8g+4b+j so the post-softmax P
// registers are already in exact B-fragment order for the PV mfma -> P
// never touches LDS. 2-phase prefetch (T3-minimum): double-buffered K/V
// LDS, next tile's global_load_lds issued before current tile's compute,
// ONE barrier per tile (syncthreads drains vmcnt). P-pack and epilogue
// use v_cvt_pk_bf16_f32 (8 ops replace ~64 scalar-RNE VALU ops per iter).

#define ATTN_STAGE(KS, VS, KVOFF)                                          \
  if ((KVOFF) < N_SEQ) {                                                   \
    _Pragma("unroll")                                                      \
    for (int call = 0; call < 2; ++call) {                                 \
      int base = (call * 4 + w) * 64;                                      \
      int c = base + lane;                                                 \
      int r = c >> 3;                                                      \
      int scb = (c & 7) ^ (r & 7);                                         \
      int pr = (r & 32) | ((r & 12) << 1) | ((r & 16) >> 2) | (r & 3);     \
      async_copy16(KS + base * 8, K + (size_t)((KVOFF) + pr) * HDIM + scb * 8); \
      async_copy16(VS + base * 8, VT + (size_t)r * N_SEQ + (KVOFF) + scb * 8);  \
    }                                                                      \
  }

#define ATTN_COMPUTE(KS, VS)                                               \
  {                                                                        \
    f32x4 s[4] = {};                                                       \
    __builtin_amdgcn_s_setprio(1);                                         \
    _Pragma("unroll")                                                      \
    for (int ks = 0; ks < 2; ++ks) {                                       \
      _Pragma("unroll")                                                    \
      for (int fn = 0; fn < 4; ++fn) {                                     \
        int r = fn * 16 + (lane & 15);                                     \
        int cb = ks * 4 + lg;                                              \
        bf16x8 kb = *(const bf16x8*)(KS + r * 64 + ((cb ^ (r & 7)) << 3)); \
        s[fn] = __builtin_amdgcn_mfma_f32_16x16x32_bf16(kb, qa[ks], s[fn], 0, 0, 0); \
      }                                                                    \
    }                                                                      \
    __builtin_amdgcn_s_setprio(0);                                         \
    float mx = s[0][0];                                                    \
    _Pragma("unroll")                                                      \
    for (int fn = 0; fn < 4; ++fn)                                         \
      _Pragma("unroll")                                                    \
      for (int j = 0; j < 4; ++j) mx = fmaxf(mx, s[fn][j]);                \
    mx = fmaxf(mx, __shfl_xor(mx, 16));                                    \
    mx = fmaxf(mx, __shfl_xor(mx, 32));                                    \
    if (__any(mx > m + 11.5416f)) {                                        \
      float mnew = fmaxf(m, mx);                                           \
      float corr = exp2_fast(m - mnew);                                    \
      m = mnew;                                                            \
      l *= corr;                                                           \
      _Pragma("unroll")                                                    \
      for (int fd = 0; fd < 4; ++fd)                                       \
        _Pragma("unroll")                                                  \
        for (int j = 0; j < 4; ++j) o[fd][j] *= corr;                      \
    }                                                                      \
    float rs = 0.f;                                                        \
    _Pragma("unroll")                                                      \
    for (int fn = 0; fn < 4; ++fn)                                         \
      _Pragma("unroll")                                                    \
      for (int j = 0; j < 4; ++j) {                                        \
        float p = exp2_fast(s[fn][j] - m);                                 \
        s[fn][j] = p; rs += p;                                             \
      }                                                                    \
    rs += __shfl_xor(rs, 16);                                              \
    rs += __shfl_xor(rs, 32);                                              \
    l += rs;                                                               \
    _Pragma("unroll")                                                      \
    for (int ks = 0; ks < 2; ++ks) {                                       \
      union { bf16x8 v; uint32_t u[4]; } pa;                               \
      pa.u[0] = cvtpk_bf16(s[2 * ks][0], s[2 * ks][1]);                    \
      pa.u[1] = cvtpk_bf16(s[2 * ks][2], s[2 * ks][3]);                    \
      pa.u[2] = cvtpk_bf16(s[2 * ks + 1][0], s[2 * ks + 1][1]);            \
      pa.u[3] = cvtpk_bf16(s[2 * ks + 1][2], s[2 * ks + 1][3]);            \
      __builtin_amdgcn_s_setprio(1);                                       \
      _Pragma("unroll")                                                    \
      for (int fd = 0; fd < 4; ++fd) {                                     \
        int rv = fd * 16 + (lane & 15);                                    \
        int cb = ks * 4 + lg;                                              \
        bf16x8 vb = *(const bf16x8*)(VS + rv * 64 + ((cb ^ (rv & 7)) << 3)); \
        o[fd] = __builtin_amdgcn_mfma_f32_16x16x32_bf16(vb, pa.v, o[fd], 0, 0, 0); \
      }                                                                    \
      __builtin_amdgcn_s_setprio(0);                                       \
    }                                                                      \
  }

__global__ __launch_bounds__(256) void attn_kernel(
    const u16* __restrict__ q, const u16* __restrict__ k,
    const u16* __restrict__ vT, u16* __restrict__ attn_out) {
  const int tid = threadIdx.x, w = tid >> 6, lane = tid & 63;
  // bijective XCD-chunked swizzle: 1024 blocks, 128 consecutive per XCD
  const int swz = (blockIdx.x & 7) * 128 + (blockIdx.x >> 3);
  const int bh = swz >> 5;            // 0..31  (b*NH + h)
  const int qt = swz & 31;
  const int b = bh >> 4, h = bh & 15;
  const u16* Q  = q  + (size_t)bh * N_SEQ * HDIM;
  const u16* K  = k  + (size_t)bh * N_SEQ * HDIM;
  const u16* VT = vT + (size_t)bh * HDIM * N_SEQ;
  const int q0 = qt * 64;
  const int lg = lane >> 4;           // 16-lane group 0..3

  __shared__ __align__(16) u16 Ks0[64 * 64];
  __shared__ __align__(16) u16 Ks1[64 * 64];
  __shared__ __align__(16) u16 VTs0[64 * 64];
  __shared__ __align__(16) u16 VTs1[64 * 64];

  // Q B-fragments in registers: lane holds Q[q0+w*16+(lane&15)][d-chunk]
  bf16x8 qa[2];
  {
    int qrow = q0 + w * 16 + (lane & 15);
    #pragma unroll
    for (int ks = 0; ks < 2; ++ks)
      qa[ks] = *(const bf16x8*)(Q + (size_t)qrow * HDIM + ks * 32 + lg * 8);
  }

  f32x4 o[4] = {};                    // O^T frag: d = fd*16 + 4*lg + j
  float m = -1e30f, l = 0.f;

  ATTN_STAGE(Ks0, VTs0, 0);
  __syncthreads();                    // drains vmcnt(0) for tile 0
  for (int kv0 = 0; kv0 < N_SEQ; kv0 += 128) {
    ATTN_STAGE(Ks1, VTs1, kv0 + 64);  // prefetch next (overlaps compute)
    ATTN_COMPUTE(Ks0, VTs0);
    __syncthreads();                  // vmcnt(0): Ks1 ready; Ks0 reads done
    ATTN_STAGE(Ks0, VTs0, kv0 + 128);
    ATTN_COMPUTE(Ks1, VTs1);
    __syncthreads();
  }

  // epilogue: O^T/l -> attn_out (B*N, C) bf16. Lane owns one q-row;
  // its 4 d-values per fd are contiguous -> 8B stores.
  float inv = 1.0f / l;
  int qrow = q0 + w * 16 + (lane & 15);
  u16* dst = attn_out + ((size_t)(b * N_SEQ + qrow)) * CDIM + h * HDIM;
  #pragma unroll
  for (int fd = 0; fd < 4; ++fd) {
    uint32_t ov[2];
    ov[0] = cvtpk_bf16(o[fd][0] * inv, o[fd][1] * inv);
    ov[1] = cvtpk_bf16(o[fd][2] * inv, o[fd][3] * inv);
    *(uint2*)(dst + fd * 16 + (lg << 2)) = *(uint2*)ov;
  }
}

// -------------------------------------------------------------- launch
extern "C" void kernel_launch(void* const* d_in, const int* in_sizes, int n_in,
                              void* d_out, int out_size, void* d_ws, size_t ws_size,
                              hipStream_t stream) {
  (void)in_sizes; (void)n_in; (void)out_size; (void)ws_size;
  const float* x      = (const float*)d_in[0];
  const float* w_qkv  = (const float*)d_in[1];
  const float* w_proj = (const float*)d_in[2];
  const float* b_proj = (const float*)d_in[3];
  float* out = (float*)d_out;

  char* ws = (char*)d_ws;
  // workspace layout (bytes)
  u16* xb     = (u16*)(ws);                       //  8.39 MB (B*N, C)
  u16* wqkvb  = (u16*)(ws + 8388608);             //  6.29 MB (3C, C)
  u16* wprojb = (u16*)(ws + 14680064);            //  2.10 MB (C, C)
  u16* qd     = (u16*)(ws + 16777216);            //  8.39 MB (B,H,N,HD)
  u16* kd     = (u16*)(ws + 25165824);            //  8.39 MB (B,H,N,HD)
  u16* vTd    = (u16*)(ws + 33554432);            //  8.39 MB (B,H,HD,N)
  u16* attn_o = (u16*)(ws + 41943040);            //  8.39 MB (B*N, C)

  cast_f2b_kernel<<<3072, 256, 0, stream>>>(w_qkv, wqkvb, 3 * CDIM * CDIM);
  cast_f2b_kernel<<<1024, 256, 0, stream>>>(w_proj, wprojb, CDIM * CDIM);
  cast_x_kernel<<<4096, 256, 0, stream>>>(x, xb);

  gemm_qkv_kernel<<<dim3(24, 32), 256, 0, stream>>>(xb, wqkvb, qd, kd, vTd);
  attn_kernel<<<1024, 256, 0, stream>>>(qd, kd, vTd, attn_o);
  gemm_proj_kernel<<<dim3(8, 64), 256, 0, stream>>>(attn_o, wprojb, b_proj, out);
}

// Round 13
// 195.368 us; speedup vs baseline: 1.4028x; 1.1092x over previous
//
#include <hip/hip_runtime.h>
#include <hip/hip_bf16.h>
#include <stdint.h>

// Problem constants
#define N_SEQ 2048
#define BATCH 2
#define CDIM  1024
#define NH    16
#define HDIM  64
// softmax pre-scale: HD^-0.5 * log2(e)  (lets us use raw v_exp_f32 = 2^x)
#define SM_PRESCALE 0.18033688f

typedef __attribute__((ext_vector_type(8))) short bf16x8;  // 8 bf16 = 4 VGPRs
typedef __attribute__((ext_vector_type(4))) float f32x4;
typedef unsigned short u16;

__device__ __forceinline__ u16 f2bf(float f) {
  union { float f; unsigned u; } v; v.f = f;
  unsigned r = v.u + 0x7fffu + ((v.u >> 16) & 1u);   // RNE
  return (u16)(r >> 16);
}

__device__ __forceinline__ float exp2_fast(float x) {
  float r;
  asm("v_exp_f32 %0, %1" : "=v"(r) : "v"(x));
  return r;
}

// pack 2 f32 -> 2 bf16 in one u32 (D[15:0]=bf16(lo), D[31:16]=bf16(hi))
__device__ __forceinline__ uint32_t cvtpk_bf16(float lo, float hi) {
  uint32_t r;
  asm("v_cvt_pk_bf16_f32 %0, %1, %2" : "=v"(r) : "v"(lo), "v"(hi));
  return r;
}

// async global->LDS, 16B per lane. lds ptr must be wave-uniform base.
__device__ __forceinline__ void async_copy16(void* l, const void* g) {
  __builtin_amdgcn_global_load_lds(
      (const __attribute__((address_space(1))) unsigned int*)g,
      (__attribute__((address_space(3))) unsigned int*)l, 16, 0, 0);
}

// ---------------------------------------------------------------- casts
__global__ __launch_bounds__(256) void cast_f2b_kernel(
    const float* __restrict__ in, u16* __restrict__ out, int n) {
  int i = (blockIdx.x * 256 + threadIdx.x) * 4;
  if (i >= n) return;
  float4 v = *(const float4*)(in + i);
  ushort4 o;
  o.x = f2bf(v.x); o.y = f2bf(v.y); o.z = f2bf(v.z); o.w = f2bf(v.w);
  *(ushort4*)(out + i) = o;
}

// x (N,B,C) fp32 -> xb (B,N,C) bf16
__global__ __launch_bounds__(256) void cast_x_kernel(
    const float* __restrict__ x, u16* __restrict__ xb) {
  int i = blockIdx.x * 256 + threadIdx.x;       // over (n*B+b) * C/4
  int c  = (i & 255) << 2;                      // C/4 = 256 float4 groups
  int nb = i >> 8;                              // n*BATCH + b
  int n = nb >> 1, b = nb & 1;
  float4 v = *(const float4*)(x + (size_t)nb * CDIM + c);
  ushort4 o;
  o.x = f2bf(v.x); o.y = f2bf(v.y); o.z = f2bf(v.z); o.w = f2bf(v.w);
  *(ushort4*)(xb + ((size_t)(b * N_SEQ + n) * CDIM) + c) = o;
}

// ---------------------------------------------------- shared GEMM core
// C[M,N] = A[M,K] @ B[N,K]^T, bf16 in, f32 acc. Block = (FM*32) x 128,
// BK=64, 4 waves in 2x2, each wave (FM*16) x 64 = FM x 4 frags of
// 16x16x32 MFMA. LDS XOR-swizzle via pre-swizzled global source
// (global_load_lds writes linearly) + swizzled ds_read.
// TR=false: D[row]=A-rows (acc col = lane&15 -> B row).
// TR=true : operands swapped -> D rows = B(weight) rows, D cols = A rows.
template<int FM, bool TR>
__device__ __forceinline__ void gemm_core_t(
    const u16* __restrict__ A, const u16* __restrict__ B,
    int arow0, int brow0, int K,
    u16* lA, u16* lB, f32x4 acc[FM][4]) {
  const int tid = threadIdx.x;
  const int w = tid >> 6, lane = tid & 63;
  const int wm = w >> 1, wn = w & 1;
  for (int k0 = 0; k0 < K; k0 += 64) {
    __syncthreads();   // protect prev iteration's reads (WAR)
    #pragma unroll
    for (int call = 0; call < FM; ++call) {    // A: FM*32 rows * 8 chunks
      int base = (call * 4 + w) * 64;          // wave-uniform chunk base
      int c = base + lane;                     // 16B chunk id, 8 per row
      int r = c >> 3;
      int scb = (c & 7) ^ (r & 7);             // pre-swizzled source chunk
      async_copy16(lA + base * 8, A + (size_t)(arow0 + r) * K + k0 + scb * 8);
    }
    #pragma unroll
    for (int call = 0; call < 4; ++call) {     // B: 128 rows * 8 chunks
      int base = (call * 4 + w) * 64;
      int c = base + lane;
      int r = c >> 3;
      int scb = (c & 7) ^ (r & 7);
      async_copy16(lB + base * 8, B + (size_t)(brow0 + r) * K + k0 + scb * 8);
    }
    __syncthreads();   // drains vmcnt(0) before barrier (compiler-emitted)
    #pragma unroll
    for (int ks = 0; ks < 2; ++ks) {
      bf16x8 af[FM], bf[4];
      #pragma unroll
      for (int i = 0; i < FM; ++i) {
        int cb = ks * 4 + (lane >> 4);
        int ra = wm * (FM * 16) + i * 16 + (lane & 15);
        af[i] = *(const bf16x8*)(lA + ra * 64 + ((cb ^ (ra & 7)) << 3));
      }
      #pragma unroll
      for (int i = 0; i < 4; ++i) {
        int cb = ks * 4 + (lane >> 4);
        int rb = wn * 64 + i * 16 + (lane & 15);
        bf[i] = *(const bf16x8*)(lB + rb * 64 + ((cb ^ (rb & 7)) << 3));
      }
      #pragma unroll
      for (int i = 0; i < FM; ++i)
        #pragma unroll
        for (int j = 0; j < 4; ++j) {
          if constexpr (TR)
            acc[i][j] = __builtin_amdgcn_mfma_f32_16x16x32_bf16(
                bf[j], af[i], acc[i][j], 0, 0, 0);
          else
            acc[i][j] = __builtin_amdgcn_mfma_f32_16x16x32_bf16(
                af[i], bf[j], acc[i][j], 0, 0, 0);
        }
    }
  }
}

// ------------------------------------------------------------- GEMM 1
// xb (4096,1024) @ w_qkv(3072,1024)^T, computed TRANSPOSED (D rows =
// weight channels, D cols = xb rows) so the epilogue writes:
//   Q/K: one 8B uint2 per frag (4 consecutive d per lane)
//   V^T: 16-lane-contiguous u16 runs (32B) instead of 4KB-stride scatter.
// q pre-scaled by SCALE*log2e for the exp2 softmax.
__global__ __launch_bounds__(256) void gemm_qkv_kernel(
    const u16* __restrict__ A, const u16* __restrict__ B,
    u16* __restrict__ qo, u16* __restrict__ ko, u16* __restrict__ vTo) {
  __shared__ __align__(16) u16 lA[128 * 64];
  __shared__ __align__(16) u16 lB[128 * 64];
  f32x4 acc[4][4] = {};
  const int arow0 = blockIdx.y * 128;
  const int brow0 = blockIdx.x * 128;
  gemm_core_t<4, true>(A, B, arow0, brow0, CDIM, lA, lB, acc);

  const int lane = threadIdx.x & 63;
  const int lg = lane >> 4;
  const int w = threadIdx.x >> 6;
  const int wm = w >> 1, wn = w & 1;
  #pragma unroll
  for (int fn = 0; fn < 4; ++fn) {
    int col0 = brow0 + wn * 64 + fn * 16;       // 16-aligned channel base
    int sel = col0 >> 10;                       // 0=q 1=k 2=v (uniform)
    int h   = (col0 >> 6) & 15;                 // head (uniform per frag)
    int d0  = (col0 & 63) + (lg << 2);          // this lane's 4 d-values
    #pragma unroll
    for (int fm = 0; fm < 4; ++fm) {
      int row = arow0 + wm * 64 + fm * 16 + (lane & 15);  // xb row
      int b = row >> 11, n = row & (N_SEQ - 1);
      size_t head = (size_t)(b * NH + h);
      f32x4 v = acc[fm][fn];
      if (sel == 0) {
        uint32_t p[2];
        p[0] = cvtpk_bf16(v[0] * SM_PRESCALE, v[1] * SM_PRESCALE);
        p[1] = cvtpk_bf16(v[2] * SM_PRESCALE, v[3] * SM_PRESCALE);
        *(uint2*)(qo + (head * N_SEQ + n) * HDIM + d0) = *(uint2*)p;
      } else if (sel == 1) {
        uint32_t p[2];
        p[0] = cvtpk_bf16(v[0], v[1]);
        p[1] = cvtpk_bf16(v[2], v[3]);
        *(uint2*)(ko + (head * N_SEQ + n) * HDIM + d0) = *(uint2*)p;
      } else {
        #pragma unroll
        for (int j = 0; j < 4; ++j)
          vTo[(head * HDIM + d0 + j) * N_SEQ + n] = f2bf(v[j]);
      }
    }
  }
}

// ------------------------------------------------------------- GEMM 2
// attn_out (4096,1024) @ w_proj(1024,1024)^T + b_proj -> out (N,B,C) fp32
// BM=64 tiles -> 512 blocks = 2/CU.
__global__ __launch_bounds__(256) void gemm_proj_kernel(
    const u16* __restrict__ A, const u16* __restrict__ B,
    const float* __restrict__ bias, float* __restrict__ out) {
  __shared__ __align__(16) u16 lA[64 * 64];
  __shared__ __align__(16) u16 lB[128 * 64];
  f32x4 acc[2][4] = {};
  const int arow0 = blockIdx.y * 64;
  const int brow0 = blockIdx.x * 128;
  gemm_core_t<2, false>(A, B, arow0, brow0, CDIM, lA, lB, acc);

  const int lane = threadIdx.x & 63;
  const int w = threadIdx.x >> 6;
  const int wm = w >> 1, wn = w & 1;
  #pragma unroll
  for (int fn = 0; fn < 4; ++fn) {
    int col = brow0 + wn * 64 + fn * 16 + (lane & 15);
    float bv = bias[col];
    #pragma unroll
    for (int fm = 0; fm < 2; ++fm) {
      #pragma unroll
      for (int j = 0; j < 4; ++j) {
        int row = arow0 + wm * 32 + fm * 16 + ((lane >> 4) << 2) + j;
        int b = row >> 11, n = row & (N_SEQ - 1);
        out[((size_t)n * BATCH + b) * CDIM + col] = acc[fm][fn][j] + bv;
      }
    }
  }
}

// ---------------------------------------------------- flash attention
// 8 waves / block, QBLK=128 (wave owns 16 q-rows): K/V staged once per
// 128 q-rows -> staging LDS-writes, L2 reads and HBM FETCH halve vs the
// 4-wave QBLK=64 version. Swapped QK^T (S^T = mfma(K,Q)): lane owns one
// q-row; pi-permuted K staging makes post-softmax P regs land in exact
// B-frag order -> P never touches LDS. 2-phase dbuf prefetch, one
// barrier per tile. cvt_pk for P-pack and epilogue.

#define ATTN_STAGE(KS, VS, KVOFF)                                          \
  if ((KVOFF) < N_SEQ) {                                                   \
    int base = w * 64;                          /* 8 waves x 64 chunks */  \
    int c = base + lane;                                                   \
    int r = c >> 3;                                                        \
    int scb = (c & 7) ^ (r & 7);                                           \
    int pr = (r & 32) | ((r & 12) << 1) | ((r & 16) >> 2) | (r & 3);       \
    async_copy16(KS + base * 8, K + (size_t)((KVOFF) + pr) * HDIM + scb * 8); \
    async_copy16(VS + base * 8, VT + (size_t)r * N_SEQ + (KVOFF) + scb * 8);  \
  }

#define ATTN_COMPUTE(KS, VS)                                               \
  {                                                                        \
    f32x4 s[4] = {};                                                       \
    __builtin_amdgcn_s_setprio(1);                                         \
    _Pragma("unroll")                                                      \
    for (int ks = 0; ks < 2; ++ks) {                                       \
      _Pragma("unroll")                                                    \
      for (int fn = 0; fn < 4; ++fn) {                                     \
        int r = fn * 16 + (lane & 15);                                     \
        int cb = ks * 4 + lg;                                              \
        bf16x8 kb = *(const bf16x8*)(KS + r * 64 + ((cb ^ (r & 7)) << 3)); \
        s[fn] = __builtin_amdgcn_mfma_f32_16x16x32_bf16(kb, qa[ks], s[fn], 0, 0, 0); \
      }                                                                    \
    }                                                                      \
    __builtin_amdgcn_s_setprio(0);                                         \
    float mx = s[0][0];                                                    \
    _Pragma("unroll")                                                      \
    for (int fn = 0; fn < 4; ++fn)                                         \
      _Pragma("unroll")                                                    \
      for (int j = 0; j < 4; ++j) mx = fmaxf(mx, s[fn][j]);                \
    mx = fmaxf(mx, __shfl_xor(mx, 16));                                    \
    mx = fmaxf(mx, __shfl_xor(mx, 32));                                    \
    if (__any(mx > m + 11.5416f)) {                                        \
      float mnew = fmaxf(m, mx);                                           \
      float corr = exp2_fast(m - mnew);                                    \
      m = mnew;                                                            \
      l *= corr;                                                           \
      _Pragma("unroll")                                                    \
      for (int fd = 0; fd < 4; ++fd)                                       \
        _Pragma("unroll")                                                  \
        for (int j = 0; j < 4; ++j) o[fd][j] *= corr;                      \
    }                                                                      \
    float rs = 0.f;                                                        \
    _Pragma("unroll")                                                      \
    for (int fn = 0; fn < 4; ++fn)                                         \
      _Pragma("unroll")                                                    \
      for (int j = 0; j < 4; ++j) {                                        \
        float p = exp2_fast(s[fn][j] - m);                                 \
        s[fn][j] = p; rs += p;                                             \
      }                                                                    \
    rs += __shfl_xor(rs, 16);                                              \
    rs += __shfl_xor(rs, 32);                                              \
    l += rs;                                                               \
    _Pragma("unroll")                                                      \
    for (int ks = 0; ks < 2; ++ks) {                                       \
      union { bf16x8 v; uint32_t u[4]; } pa;                               \
      pa.u[0] = cvtpk_bf16(s[2 * ks][0], s[2 * ks][1]);                    \
      pa.u[1] = cvtpk_bf16(s[2 * ks][2], s[2 * ks][3]);                    \
      pa.u[2] = cvtpk_bf16(s[2 * ks + 1][0], s[2 * ks + 1][1]);            \
      pa.u[3] = cvtpk_bf16(s[2 * ks + 1][2], s[2 * ks + 1][3]);            \
      __builtin_amdgcn_s_setprio(1);                                       \
      _Pragma("unroll")                                                    \
      for (int fd = 0; fd < 4; ++fd) {                                     \
        int rv = fd * 16 + (lane & 15);                                    \
        int cb = ks * 4 + lg;                                              \
        bf16x8 vb = *(const bf16x8*)(VS + rv * 64 + ((cb ^ (rv & 7)) << 3)); \
        o[fd] = __builtin_amdgcn_mfma_f32_16x16x32_bf16(vb, pa.v, o[fd], 0, 0, 0); \
      }                                                                    \
      __builtin_amdgcn_s_setprio(0);                                       \
    }                                                                      \
  }

__global__ __launch_bounds__(512) void attn_kernel(
    const u16* __restrict__ q, const u16* __restrict__ k,
    const u16* __restrict__ vT, u16* __restrict__ attn_out) {
  const int tid = threadIdx.x, w = tid >> 6, lane = tid & 63;
  // bijective XCD-chunked swizzle: 512 blocks, 64 consecutive per XCD
  const int swz = (blockIdx.x & 7) * 64 + (blockIdx.x >> 3);
  const int bh = swz >> 4;            // 0..31  (b*NH + h)
  const int qt = swz & 15;            // 16 q-tiles of 128
  const int b = bh >> 4, h = bh & 15;
  const u16* Q  = q  + (size_t)bh * N_SEQ * HDIM;
  const u16* K  = k  + (size_t)bh * N_SEQ * HDIM;
  const u16* VT = vT + (size_t)bh * HDIM * N_SEQ;
  const int q0 = qt * 128;
  const int lg = lane >> 4;           // 16-lane group 0..3

  __shared__ __align__(16) u16 Ks0[64 * 64];
  __shared__ __align__(16) u16 Ks1[64 * 64];
  __shared__ __align__(16) u16 VTs0[64 * 64];
  __shared__ __align__(16) u16 VTs1[64 * 64];

  // Q B-fragments in registers: lane holds Q[q0+w*16+(lane&15)][d-chunk]
  bf16x8 qa[2];
  {
    int qrow = q0 + w * 16 + (lane & 15);
    #pragma unroll
    for (int ks = 0; ks < 2; ++ks)
      qa[ks] = *(const bf16x8*)(Q + (size_t)qrow * HDIM + ks * 32 + lg * 8);
  }

  f32x4 o[4] = {};                    // O^T frag: d = fd*16 + 4*lg + j
  float m = -1e30f, l = 0.f;

  ATTN_STAGE(Ks0, VTs0, 0);
  __syncthreads();                    // drains vmcnt(0) for tile 0
  for (int kv0 = 0; kv0 < N_SEQ; kv0 += 128) {
    ATTN_STAGE(Ks1, VTs1, kv0 + 64);  // prefetch next (overlaps compute)
    ATTN_COMPUTE(Ks0, VTs0);
    __syncthreads();                  // vmcnt(0): Ks1 ready; Ks0 reads done
    ATTN_STAGE(Ks0, VTs0, kv0 + 128);
    ATTN_COMPUTE(Ks1, VTs1);
    __syncthreads();
  }

  // epilogue: O^T/l -> attn_out (B*N, C) bf16. Lane owns one q-row;
  // its 4 d-values per fd are contiguous -> 8B stores.
  float inv = 1.0f / l;
  int qrow = q0 + w * 16 + (lane & 15);
  u16* dst = attn_out + ((size_t)(b * N_SEQ + qrow)) * CDIM + h * HDIM;
  #pragma unroll
  for (int fd = 0; fd < 4; ++fd) {
    uint32_t ov[2];
    ov[0] = cvtpk_bf16(o[fd][0] * inv, o[fd][1] * inv);
    ov[1] = cvtpk_bf16(o[fd][2] * inv, o[fd][3] * inv);
    *(uint2*)(dst + fd * 16 + (lg << 2)) = *(uint2*)ov;
  }
}

// -------------------------------------------------------------- launch
extern "C" void kernel_launch(void* const* d_in, const int* in_sizes, int n_in,
                              void* d_out, int out_size, void* d_ws, size_t ws_size,
                              hipStream_t stream) {
  (void)in_sizes; (void)n_in; (void)out_size; (void)ws_size;
  const float* x      = (const float*)d_in[0];
  const float* w_qkv  = (const float*)d_in[1];
  const float* w_proj = (const float*)d_in[2];
  const float* b_proj = (const float*)d_in[3];
  float* out = (float*)d_out;

  char* ws = (char*)d_ws;
  // workspace layout (bytes)
  u16* xb     = (u16*)(ws);                       //  8.39 MB (B*N, C)
  u16* wqkvb  = (u16*)(ws + 8388608);             //  6.29 MB (3C, C)
  u16* wprojb = (u16*)(ws + 14680064);            //  2.10 MB (C, C)
  u16* qd     = (u16*)(ws + 16777216);            //  8.39 MB (B,H,N,HD)
  u16* kd     = (u16*)(ws + 25165824);            //  8.39 MB (B,H,N,HD)
  u16* vTd    = (u16*)(ws + 33554432);            //  8.39 MB (B,H,HD,N)
  u16* attn_o = (u16*)(ws + 41943040);            //  8.39 MB (B*N, C)

  cast_f2b_kernel<<<3072, 256, 0, stream>>>(w_qkv, wqkvb, 3 * CDIM * CDIM);
  cast_f2b_kernel<<<1024, 256, 0, stream>>>(w_proj, wprojb, CDIM * CDIM);
  cast_x_kernel<<<4096, 256, 0, stream>>>(x, xb);

  gemm_qkv_kernel<<<dim3(24, 32), 256, 0, stream>>>(xb, wqkvb, qd, kd, vTd);
  attn_kernel<<<512, 512, 0, stream>>>(qd, kd, vTd, attn_o);
  gemm_proj_kernel<<<dim3(8, 64), 256, 0, stream>>>(attn_o, wprojb, b_proj, out);
}